// Round 4
// baseline (115.747 us; speedup 1.0000x reference)
//
#include <hip/hip_runtime.h>
#include <math.h>

// Problem: B=4,S=2048,D=2048,E=64,K=2 -> tokens 8192, K-dim 2048, experts 64
#define NTOK 8192
#define DDIM 2048
#define NEXP 64
#define MT   32            // tokens per block (2 MFMA m-tiles)
#define ASTR 40            // staged-row stride in halves (32 data + 8 pad; 80B)
#define XLO  (32 * ASTR)   // lo-plane offset within a wave's staging (halves)
#define WST  (2 * 32 * ASTR) // per-wave staging halves (hi+lo) = 2560
#define CSTR 66            // partial-buffer row stride (floats)

#define GATED_SZ (NTOK * NEXP)
#define IDX_OFF  GATED_SZ
#define VALS_OFF (GATED_SZ + NTOK * 2)

#define NKSTEP (DDIM / 32)            // 64 MFMA k-steps
#define NTILE  (NEXP / 16)            // 4 n-tiles
#define BFRAG_HALVES ((size_t)NKSTEP * NTILE * 64 * 8)   // 131072 halves

typedef _Float16 f16x8 __attribute__((ext_vector_type(8)));
typedef _Float16 f16x4 __attribute__((ext_vector_type(4)));
typedef float    f32x4 __attribute__((ext_vector_type(4)));

// ---------------------------------------------------------------------------
// Pack W [E=64][D=2048] into MFMA B-fragments (fp16 hi + 4096-scaled lo).
// Frag (ks, nt): lane holds B[k=ks*32+(lane>>4)*8+j][n=nt*16+(lane&15)].
// Layout: Bh[((ks*4+nt)*64+lane)*8 + j]. (Verified absmax-stable.)
// ---------------------------------------------------------------------------
__global__ void pack_b_kernel(const float* __restrict__ W,
                              _Float16* __restrict__ Bh,
                              _Float16* __restrict__ Bl)
{
    const int tid  = blockIdx.x * blockDim.x + threadIdx.x;  // 0..16383
    const int lane = tid & 63;
    const int fid  = tid >> 6;
    const int ks   = fid >> 2;
    const int nt   = fid & 3;
    const int e    = nt * 16 + (lane & 15);
    const int k    = ks * 32 + (lane >> 4) * 8;
    const float* src = W + (size_t)e * DDIM + k;

    f16x8 hi, lo;
#pragma unroll
    for (int j = 0; j < 8; ++j) {
        const float v = src[j];
        const _Float16 h = (_Float16)v;
        hi[j] = h;
        lo[j] = (_Float16)((v - (float)h) * 4096.f);
    }
    *(f16x8*)(Bh + (size_t)tid * 8) = hi;
    *(f16x8*)(Bl + (size_t)tid * 8) = lo;
}

#define BFRAG(base, ks, nt) \
    (*(const f16x8*)((base) + ((((size_t)(ks)) * 4 + (nt)) * 64 + lane) * 8))

// fp32x4 -> fp16 hi + 4096-scaled lo residual (same split as pack_b).
static __device__ __forceinline__ void cvt_hilo4(float4 v, f16x4& h4, f16x4& l4)
{
    const float vv[4] = {v.x, v.y, v.z, v.w};
#pragma unroll
    for (int j = 0; j < 4; ++j) {
        const _Float16 hh = (_Float16)vv[j];
        h4[j] = hh;
        l4[j] = (_Float16)((vv[j] - (float)hh) * 4096.f);
    }
}

// ---------------------------------------------------------------------------
// Fused gate kernel. 256 blocks x 1024 thr (16 waves, 1 block/CU, 4 w/SIMD).
// Round-4 change: MT 16 -> 32. A block covers 32 tokens x 64 experts; wave w
// owns k-slice [w*128, w*128+128) for BOTH 16-token m-tiles. Per-CU B-frag
// L2 traffic halves (1 MB -> 512 KB; per-CU ingest 1.28 -> 0.78 MB) and the
// per-wave MFMA : B-load ratio doubles (96 : 32) -> each L2-latency stall
// has 2x the compute to hide under. Main loop stays BARRIER-FREE with
// per-wave private LDS staging (in-order per-wave ds ops give RAW/WAR
// ordering; verified in rounds 2-3). 4 sub-chunks of 32k, single staging
// buffer reused (load of chunk s+1 is in flight during compute of chunk s).
// logits = acc_hh + 2^-12 * acc_lo (x_lo, w_lo pre-scaled by 4096).
// Epilogue: 16 k-slice partials summed ascending (deterministic), noise,
// top-2, softmax -- logic unchanged from the verified round-3 kernel.
// ---------------------------------------------------------------------------
__global__ __launch_bounds__(1024, 4) void gate_kernel(
    const float* __restrict__ x,
    const _Float16* __restrict__ Bh,
    const _Float16* __restrict__ Bl,
    const float* __restrict__ noise_w,
    const float* __restrict__ noise,
    float* __restrict__ out)
{
    // staging: 16 waves x 2560 halves = 81920 B.
    // cbuf (after barrier, aliased): 16 partials x 32 tok x CSTR x 4B = 135168 B.
    __shared__ __align__(16) char smem_raw[16 * 32 * CSTR * 4];

    const int tid  = threadIdx.x;
    const int lane = tid & 63;
    const int w    = __builtin_amdgcn_readfirstlane(tid >> 6);  // k-slice 0..15
    const int tokBase = blockIdx.x * MT;

    const int q = lane >> 4;               // 0..3
    const int m = lane & 15;               // 0..15

    _Float16* xs = (_Float16*)smem_raw + (size_t)w * WST;

    // staging geometry: piece p covers rows p*8+(lane>>3), cols (lane&7)*4
    // (8 lanes span 128B contiguous -> coalesced; 32 rows x 32 floats/chunk)
    const int srow = tid & 0 ? 0 : (lane >> 3);   // 0..7 within piece
    const int scol = (lane & 7) * 4;              // 0..28
    const float* xw = x + (size_t)tokBase * DDIM + (size_t)w * 128;

    // hoisted epilogue operands
    const float nwv = noise_w[lane];
    const float nz0 = noise[(size_t)(tokBase + w * 2)     * NEXP + lane];
    const float nz1 = noise[(size_t)(tokBase + w * 2 + 1) * NEXP + lane];

    f32x4 acc_hh[2][4], acc_lo[2][4];
#pragma unroll
    for (int mt = 0; mt < 2; ++mt)
#pragma unroll
        for (int nt = 0; nt < 4; ++nt) {
            acc_hh[mt][nt] = (f32x4){0.f, 0.f, 0.f, 0.f};
            acc_lo[mt][nt] = (f32x4){0.f, 0.f, 0.f, 0.f};
        }

    // chunk s = 32 k; k = w*128 + s*32 + [0,32)
#define LOADSUB(s)                                                           \
    _Pragma("unroll")                                                        \
    for (int p = 0; p < 4; ++p) {                                            \
        rA[p] = *(const float4*)(xw + (size_t)(p * 8 + srow) * DDIM          \
                                 + (s) * 32 + scol);                         \
    }

#define STAGESUB()                                                           \
    _Pragma("unroll")                                                        \
    for (int p = 0; p < 4; ++p) {                                            \
        f16x4 h4, l4;                                                        \
        cvt_hilo4(rA[p], h4, l4);                                            \
        const int off = (p * 8 + srow) * ASTR + scol;                        \
        *(f16x4*)&xs[off] = h4;                                              \
        *(f16x4*)&xs[XLO + off] = l4;                                        \
    }

    // chunk s = one 32-k MFMA step: ks = w*4 + s; 2 m-tiles x 4 n-tiles
#define COMPUTESUB(s)                                                        \
    {                                                                        \
        const int ks = w * 4 + (s);                                          \
        _Pragma("unroll")                                                    \
        for (int mt = 0; mt < 2; ++mt) {                                     \
            const f16x8 ah = *(const f16x8*)&xs[(mt * 16 + m) * ASTR + q * 8]; \
            const f16x8 al = *(const f16x8*)&xs[XLO + (mt * 16 + m) * ASTR + q * 8]; \
            _Pragma("unroll")                                                \
            for (int nt = 0; nt < 4; ++nt) {                                 \
                const f16x8 bh = BFRAG(Bh, ks, nt);                          \
                const f16x8 bl = BFRAG(Bl, ks, nt);                          \
                acc_hh[mt][nt] = __builtin_amdgcn_mfma_f32_16x16x32_f16(ah, bh, acc_hh[mt][nt], 0, 0, 0); \
                acc_lo[mt][nt] = __builtin_amdgcn_mfma_f32_16x16x32_f16(ah, bl, acc_lo[mt][nt], 0, 0, 0); \
                acc_lo[mt][nt] = __builtin_amdgcn_mfma_f32_16x16x32_f16(al, bh, acc_lo[mt][nt], 0, 0, 0); \
            }                                                                \
        }                                                                    \
    }

    float4 rA[4];
    LOADSUB(0)          // cold start: load + stage chunk 0
    STAGESUB()
    LOADSUB(1)          // chunk 1 in flight across compute(0)
    COMPUTESUB(0)
    STAGESUB()          // per-wave in-order ds: c0 reads retire before writes
    LOADSUB(2)
    COMPUTESUB(1)
    STAGESUB()
    LOADSUB(3)
    COMPUTESUB(2)
    STAGESUB()
    COMPUTESUB(3)

#undef LOADSUB
#undef STAGESUB
#undef COMPUTESUB

    // ---- epilogue: 16 k-slice partials -> cbuf (aliases staging LDS) ----
    __syncthreads();    // all waves done reading their staging regions
    float* cbuf = (float*)smem_raw;   // [16 partials][32 tokens][CSTR]

    // C/D layout: col(e)=lane&15, row within m-tile = q*4+r
#pragma unroll
    for (int mt = 0; mt < 2; ++mt)
#pragma unroll
        for (int nt = 0; nt < 4; ++nt) {
            const int e = nt * 16 + m;
#pragma unroll
            for (int r = 0; r < 4; ++r) {
                const int t = mt * 16 + q * 4 + r;
                cbuf[((w * MT) + t) * CSTR + e] =
                    acc_hh[mt][nt][r] + acc_lo[mt][nt][r] * (1.f / 4096.f);
            }
        }
    __syncthreads();

    // Epilogue: wave w owns tokens w*2, w*2+1; lane = expert.
#pragma unroll
    for (int i = 0; i < 2; ++i) {
        const int t   = w * 2 + i;
        const int tok = tokBase + t;
        const int e   = lane;

        float v = 0.f;
#pragma unroll
        for (int p = 0; p < 16; ++p)
            v += cbuf[((p * MT) + t) * CSTR + e];
        v += (i ? nz1 : nz0) * nwv;

        // top-1: butterfly max, lax.top_k tie-break (lower index wins)
        float m1 = v; int i1 = e;
#pragma unroll
        for (int sh = 32; sh > 0; sh >>= 1) {
            float ov = __shfl_xor(m1, sh, 64);
            int   oi = __shfl_xor(i1, sh, 64);
            if (ov > m1 || (ov == m1 && oi < i1)) { m1 = ov; i1 = oi; }
        }
        float vm = (e == i1) ? -INFINITY : v;
        float m2 = vm; int i2 = e;
#pragma unroll
        for (int sh = 32; sh > 0; sh >>= 1) {
            float ov = __shfl_xor(m2, sh, 64);
            int   oi = __shfl_xor(i2, sh, 64);
            if (ov > m2 || (ov == m2 && oi < i2)) { m2 = ov; i2 = oi; }
        }

        const float e2  = expf(m2 - m1);
        const float inv = 1.f / (1.f + e2);
        const float p1  = inv;
        const float p2  = e2 * inv;

        float gval = 0.f;
        if (e == i1) gval = p1;
        else if (e == i2) gval = p2;
        out[(size_t)tok * NEXP + e] = gval;

        if (lane == 0) {
            out[IDX_OFF  + tok * 2 + 0] = (float)i1;
            out[IDX_OFF  + tok * 2 + 1] = (float)i2;
            out[VALS_OFF + tok * 2 + 0] = m1;
            out[VALS_OFF + tok * 2 + 1] = m2;
        }
    }
}

extern "C" void kernel_launch(void* const* d_in, const int* in_sizes, int n_in,
                              void* d_out, int out_size, void* d_ws, size_t ws_size,
                              hipStream_t stream) {
    const float* x     = (const float*)d_in[0];
    const float* W     = (const float*)d_in[1];
    const float* nw    = (const float*)d_in[2];
    const float* noise = (const float*)d_in[3];
    // d_in[4] is k==2, hardcoded
    float* out = (float*)d_out;

    _Float16* Bh = (_Float16*)d_ws;                 // 256 KB
    _Float16* Bl = Bh + BFRAG_HALVES;               // 256 KB

    hipLaunchKernelGGL(pack_b_kernel, dim3(64), dim3(256), 0, stream, W, Bh, Bl);

    hipLaunchKernelGGL(gate_kernel, dim3(NTOK / MT), dim3(1024), 0, stream,
                       x, Bh, Bl, nw, noise, out);
}